// Round 18
// baseline (65.567 us; speedup 1.0000x reference)
//
#include <hip/hip_runtime.h>
#include <hip/hip_fp16.h>

// Encoder: per-atom top-T nearest grid points -> sum_t rbf[33] (x) (sh[9]*n*w)
// R17 lessons: accum optimum is 2048 blocks (CHA=1, revert SEGPB); deferred
// w/v loads serialize the load chain (revert). R18: hist_store atom-grouping
// (AG=4 atoms/block, one slice): grid+w/v read once per 4 atoms -> 4x less
// L2 traffic, 4x ILP. Segments/downstream unchanged.
// 6 dispatches:
// K1 hist_store: AG-atom full scan; 256-bin clamped coarse hists; append
//                bits(4B) + payload(8B f16 dx,dy,dz,nw) per (atom,slice)
// K2 scan1     : per-atom: sum 32x256-bin hists -> b1, residual R2
// K3 fine      : fine hist bits[17:9] of crossing-bin points (bits-only)
// K4 scan2     : per-atom: scan 512-bin fine hist -> thr[a]
// K5 accum     : thr scalar; prefetch records; filter, features, bf16 MFMA,
//                LDS cross-wave reduce, one plain 297-float store per block
// K6 reduce    : sum 32 chunk-partials per atom -> out

typedef float f32x4 __attribute__((ext_vector_type(4)));
typedef int   i32x4 __attribute__((ext_vector_type(4)));

#define SLICES 32
#define AG     4             // atoms per hist_store block (A % AG == 0)
#define NB1    256           // coarse bins (clamped)
#define NB2    512           // fine bins: bits[17:9] within crossing bin
#define CLAMP0 4000u         // bits>>18 below this (d2<~0.25) -> bin 0
#define NCHUNK SLICES        // accum chunks per atom (1 segment/block)
#define PBSTR  304           // partials row stride
#define CUT25  0x41C80000u   // __float_as_uint(25.0f) == CUTOFF^2 bits
#define WROWS  49            // accum: 33 A rows + 16 B rows per wave
#define BBASE  (33 * 72)     // B region offset (shorts)

__device__ __forceinline__ unsigned short tobf(float v) {
  return (unsigned short)((__float_as_uint(v) + 0x8000u) >> 16);
}

__device__ __forceinline__ unsigned pack2h(float a, float b) {
  __half2 h = __floats2half2_rn(a, b);
  return *reinterpret_cast<unsigned*>(&h);
}

__device__ __forceinline__ void mfma_acc(f32x4& d, i32x4 a, i32x4 b) {
  asm("v_mfma_f32_16x16x32_bf16 %0, %1, %2, %0" : "+v"(d) : "v"(a), "v"(b));
}

// ---------------- K1: AG-atom full scan -> coarse hists + appends ----------------
__global__ __launch_bounds__(256) void enc_hist_store(
    const float* __restrict__ nuc, const float* __restrict__ grid,
    const float* __restrict__ wv, const float* __restrict__ nv, int N,
    unsigned* __restrict__ hists, unsigned* __restrict__ cnt,
    unsigned* __restrict__ bitsArr, uint2* __restrict__ pay, int scap,
    unsigned* __restrict__ ghist2) {
  __shared__ unsigned lh[AG][NB1];
  __shared__ unsigned s_cnt[AG];
  int ag = blockIdx.x / SLICES, s = blockIdx.x % SLICES;
  int a0 = ag * AG;
  int tid = threadIdx.x, lane = tid & 63;
  if (tid < NB1) {
    #pragma unroll
    for (int aa = 0; aa < AG; ++aa) lh[aa][tid] = 0;
  }
  if (tid < AG) s_cnt[tid] = 0;
  { // zero the AG atoms' stripes of the fine hist (written by K3 later)
    const int stripe = NB2 / SLICES;       // 16
    if (tid < stripe) {
      #pragma unroll
      for (int aa = 0; aa < AG; ++aa)
        ghist2[(size_t)(a0 + aa) * NB2 + s * stripe + tid] = 0;
    }
  }
  __syncthreads();

  float pxs[AG], pys[AG], pzs[AG];
  #pragma unroll
  for (int aa = 0; aa < AG; ++aa) {
    pxs[aa] = nuc[3*(a0+aa)+0];
    pys[aa] = nuc[3*(a0+aa)+1];
    pzs[aa] = nuc[3*(a0+aa)+2];
  }
  unsigned* segb[AG];
  uint2*    segp[AG];
  #pragma unroll
  for (int aa = 0; aa < AG; ++aa) {
    size_t off = (size_t)((a0 + aa) * SLICES + s) * scap;
    segb[aa] = bitsArr + off;
    segp[aa] = pay + off;
  }
  const float4* G4 = (const float4*)grid;
  const float4* W4 = (const float4*)wv;
  const float4* V4 = (const float4*)nv;
  int nq = N >> 2;
  int qper = (nq + SLICES - 1) / SLICES;
  int qlo = s * qper, qhi = min(nq, qlo + qper);

  for (int qi = qlo + tid; qi < qhi; qi += 256) {
    float4 A4 = G4[3*qi], B4 = G4[3*qi+1], C4 = G4[3*qi+2];
    float4 w4 = W4[qi], v4 = V4[qi];
    float xs[4] = {A4.x, A4.w, B4.z, C4.y};
    float ys[4] = {A4.y, B4.x, B4.w, C4.z};
    float zs[4] = {A4.z, B4.y, C4.x, C4.w};
    float nws[4] = {v4.x * w4.x, v4.y * w4.y, v4.z * w4.z, v4.w * w4.w};
    #pragma unroll
    for (int aa = 0; aa < AG; ++aa) {
      float px = pxs[aa], py = pys[aa], pz = pzs[aa];
      float dxs[4], dys[4], dzs[4];
      unsigned bt[4];
      #pragma unroll
      for (int k = 0; k < 4; ++k) {
        float dx = px - xs[k], dy = py - ys[k], dz = pz - zs[k];
        dxs[k] = dx; dys[k] = dy; dzs[k] = dz;
        float d2 = __fmaf_rn(dx, dx, __fmaf_rn(dy, dy, __fmul_rn(dz, dz)));
        bt[k] = __float_as_uint(d2);
        if (bt[k] < CUT25) {
          int cb = (int)(bt[k] >> 18) - (int)CLAMP0;
          atomicAdd(&lh[aa][cb > 0 ? cb : 0], 1u);
        }
      }
      #pragma unroll
      for (int k = 0; k < 4; ++k) {
        bool sel = bt[k] < CUT25;                  // envelope != 0 only here
        unsigned long long mm = __ballot(sel);
        if (mm) {
          int leader = __ffsll(mm) - 1;
          unsigned base = 0;
          if (lane == leader) base = atomicAdd(&s_cnt[aa], (unsigned)__popcll(mm));
          base = __shfl(base, leader);
          if (sel) {
            unsigned pos = base + (unsigned)__popcll(mm & ((1ull << lane) - 1ull));
            if (pos < (unsigned)scap) {
              segb[aa][pos] = bt[k];
              segp[aa][pos] = make_uint2(pack2h(dxs[k], dys[k]),
                                         pack2h(dzs[k], nws[k]));
            }
          }
        }
      }
    }
  }
  if (s == SLICES - 1) {                   // scalar tail (N % 4 points)
    for (int i = 4*nq + tid; i < N; i += 256) {
      float gx = grid[3*i+0], gy = grid[3*i+1], gz = grid[3*i+2];
      float nwi = nv[i] * wv[i];
      #pragma unroll
      for (int aa = 0; aa < AG; ++aa) {
        float dx = pxs[aa] - gx, dy = pys[aa] - gy, dz = pzs[aa] - gz;
        float d2 = __fmaf_rn(dx, dx, __fmaf_rn(dy, dy, __fmul_rn(dz, dz)));
        unsigned bits = __float_as_uint(d2);
        bool sel = bits < CUT25;
        if (sel) {
          int cb = (int)(bits >> 18) - (int)CLAMP0;
          atomicAdd(&lh[aa][cb > 0 ? cb : 0], 1u);
        }
        unsigned long long mm = __ballot(sel);
        if (mm) {
          int leader = __ffsll(mm) - 1;
          unsigned base = 0;
          if (lane == leader) base = atomicAdd(&s_cnt[aa], (unsigned)__popcll(mm));
          base = __shfl(base, leader);
          if (sel) {
            unsigned pos = base + (unsigned)__popcll(mm & ((1ull << lane) - 1ull));
            if (pos < (unsigned)scap) {
              segb[aa][pos] = bits;
              segp[aa][pos] = make_uint2(pack2h(dx, dy), pack2h(dz, nwi));
            }
          }
        }
      }
    }
  }
  __syncthreads();
  if (tid < NB1) {
    #pragma unroll
    for (int aa = 0; aa < AG; ++aa)
      hists[(size_t)((a0 + aa) * SLICES + s) * NB1 + tid] = lh[aa][tid];
  }
  if (tid < AG) cnt[(a0 + tid) * SLICES + s] = s_cnt[tid];
}

// ---------------- K2: per-atom coarse scan -> b1, R2 ----------------
__global__ __launch_bounds__(256) void enc_scan1(
    const unsigned* __restrict__ hists, unsigned T,
    unsigned* __restrict__ b1r, unsigned* __restrict__ r2r) {
  __shared__ unsigned lh[NB1];
  __shared__ unsigned s_bin, s_pre;
  int a = blockIdx.x, tid = threadIdx.x;
  if (tid < NB1) {
    unsigned acc = 0;
    const unsigned* base = hists + (size_t)a * SLICES * NB1 + tid;
    #pragma unroll 8
    for (int t = 0; t < SLICES; ++t) acc += base[(size_t)t * NB1];
    lh[tid] = acc;
  }
  if (tid == 0) { s_bin = NB1 - 1; s_pre = 0; }
  __syncthreads();
  if (tid < 64) {
    int lane = tid, base = 4 * lane;
    unsigned h0 = lh[base], h1 = lh[base+1], h2 = lh[base+2], h3 = lh[base+3];
    unsigned ssum = h0 + h1 + h2 + h3;
    unsigned p = ssum;
    #pragma unroll
    for (int d = 1; d < 64; d <<= 1) {
      unsigned t = __shfl_up(p, d);
      if (lane >= d) p += t;
    }
    unsigned excl = p - ssum;
    if (excl < T && T <= p) {              // unique crossing lane
      unsigned cum = excl;
      unsigned hh[4] = {h0, h1, h2, h3};
      #pragma unroll
      for (int k = 0; k < 4; ++k) {
        if (cum + hh[k] >= T) { s_bin = (unsigned)(base + k); s_pre = cum; break; }
        cum += hh[k];
      }
    }
  }
  __syncthreads();
  if (tid == 0) { b1r[a] = s_bin; r2r[a] = T - s_pre; }
}

// ---------------- K3: fine hist of crossing-bin points (bits-only) ----------------
__global__ __launch_bounds__(256) void enc_fine(
    const unsigned* __restrict__ b1r, const unsigned* __restrict__ cnt,
    const unsigned* __restrict__ bitsArr, int scap,
    unsigned* __restrict__ ghist2) {
  int seg_id = blockIdx.x;
  int a = seg_id / SLICES;
  unsigned b1c = b1r[a];
  unsigned tb1 = b1c + CLAMP0;
  int total = min((int)cnt[seg_id], scap);
  const unsigned* segb = bitsArr + (size_t)seg_id * scap;
  unsigned* gh2 = ghist2 + (size_t)a * NB2;
  for (int i = threadIdx.x; i < total; i += 256) {
    unsigned bits = segb[i];
    unsigned cb = bits >> 18;
    bool match = b1c ? (cb == tb1) : (cb <= CLAMP0);  // bin0 = clamped region
    if (match) atomicAdd(&gh2[(bits >> 9) & (NB2 - 1)], 1u);
  }
}

// ---------------- K4: per-atom fine scan -> thr ----------------
__global__ __launch_bounds__(256) void enc_scan2(
    const unsigned* __restrict__ ghist2, const unsigned* __restrict__ b1r,
    const unsigned* __restrict__ r2r, unsigned* __restrict__ thr) {
  __shared__ unsigned lh2[NB2];
  __shared__ unsigned s_bin2;
  int a = blockIdx.x, tid = threadIdx.x;
  const unsigned* gh2 = ghist2 + (size_t)a * NB2;
  lh2[tid] = gh2[tid];
  lh2[tid + 256] = gh2[tid + 256];
  if (tid == 0) s_bin2 = NB2 - 1;
  __syncthreads();
  unsigned R = r2r[a];
  if (tid < 64) {                          // two-level scan over 512 bins
    int lane = tid, base = 8 * lane;
    unsigned hh[8], ssum = 0;
    #pragma unroll
    for (int k = 0; k < 8; ++k) { hh[k] = lh2[base + k]; ssum += hh[k]; }
    unsigned p = ssum;
    #pragma unroll
    for (int d = 1; d < 64; d <<= 1) {
      unsigned t = __shfl_up(p, d);
      if (lane >= d) p += t;
    }
    unsigned excl = p - ssum;
    if (excl < R && R <= p) {
      unsigned cum = excl;
      #pragma unroll
      for (int k = 0; k < 8; ++k) {
        if (cum + hh[k] >= R) { s_bin2 = (unsigned)(base + k); break; }
        cum += hh[k];
      }
    }
  }
  __syncthreads();
  if (tid == 0) thr[a] = ((b1r[a] + CLAMP0) << 9) | s_bin2;  // (bits>>9) <= thr
}

// ---------------- K5: MFMA accumulation -> per-block partials ----------------
__global__ __launch_bounds__(256, 5) void enc_accum(
    const unsigned* __restrict__ thrv, const unsigned* __restrict__ cnt,
    const unsigned* __restrict__ bitsArr, const uint2* __restrict__ pay,
    int scap, float* __restrict__ pb) {
  // per-wave 49-row x 72-short region: A rows 0..32, B rows 33..48.
  // MFMA a2 reads rows 32..47 -> feeds only discarded C rows. 28.2KB total.
  __shared__ __align__(16) unsigned short lds[4][WROWS * 72];
  int seg_id = blockIdx.x;
  int a = seg_id / SLICES;
  int tid = threadIdx.x, lane = tid & 63, w = tid >> 6;
  unsigned short* SB = &lds[w][0];

  { // zero this wave's region (A stale cols must not be NaN; 441 i32x4)
    i32x4 z = {0, 0, 0, 0};
    i32x4* zp = (i32x4*)SB;
    #pragma unroll
    for (int t = 0; t < 7; ++t) {
      int idx = lane + t * 64;
      if (idx < (WROWS * 72) / 8) zp[idx] = z;
    }
  }

  unsigned thr = thrv[a];                  // precomputed: no per-block scan
  int total = min((int)cnt[seg_id], scap);
  const unsigned* lstb = bitsArr + (size_t)seg_id * scap;
  const uint2*    lstp = pay     + (size_t)seg_id * scap;

  f32x4 acc0 = {0,0,0,0}, acc1 = {0,0,0,0}, acc2 = {0,0,0,0};
  int m = lane & 15, q = lane >> 4;
  const float SQRT2 = 1.41421356237309515f;
  const float PIF   = 3.14159265358979323846f;
  const float S3    = 1.73205080756887729f;

  // software prefetch: issue next record's loads before the ~600cy body
  int j0 = w * 64 + lane;
  unsigned bitsN = (j0 < total) ? lstb[j0] : 0xFFFFFFFFu;
  uint2 prN = make_uint2(0u, 0u);
  if (j0 < total) prN = lstp[j0];

  for (int jb = w * 64; jb < total; jb += 256) {
    unsigned bits = bitsN;
    uint2 pr = prN;
    int jn = jb + 256 + lane;
    if (jn < total) { bitsN = lstb[jn]; prN = lstp[jn]; }
    bool live = (jb + lane < total) && ((bits >> 9) <= thr);
    if (live) {
      float d2 = __uint_as_float(bits);
      __half2 hxy = *reinterpret_cast<const __half2*>(&pr.x);
      __half2 hzn = *reinterpret_cast<const __half2*>(&pr.y);
      float dx = __low2float(hxy), dy = __high2float(hxy);
      float dz = __low2float(hzn), nw = __high2float(hzn);
#if __has_builtin(__builtin_amdgcn_sqrtf)
      float rn = __builtin_amdgcn_sqrtf(d2) * 0.2f;
#else
      float rn = sqrtf(d2) * 0.2f;
#endif
      float x2 = rn * rn;
      float x6 = x2 * x2 * x2;
      float e  = __fmaf_rn(x6, __fmaf_rn(-21.f, x2, __fmaf_rn(48.f, rn, -28.f)), 1.f);
      float f  = SQRT2 * e;
#if __has_builtin(__builtin_amdgcn_rcpf)
      float inv = 0.2f * __builtin_amdgcn_rcpf(rn + 1e-15f);
#else
      float inv = 0.2f / (rn + 1e-15f);
#endif
      float X = dx * inv, Y = dy * inv, Z = dz * inv;
      float r2 = __fmaf_rn(X, X, __fmaf_rn(Y, Y, Z * Z));
      // B rows: v[h] = nw * sh[h]
      SB[BBASE + 0*72 + lane] = tobf(nw);
      SB[BBASE + 1*72 + lane] = tobf(nw * Y);
      SB[BBASE + 2*72 + lane] = tobf(nw * Z);
      SB[BBASE + 3*72 + lane] = tobf(nw * X);
      SB[BBASE + 4*72 + lane] = tobf(nw * S3 * X * Y);
      SB[BBASE + 5*72 + lane] = tobf(nw * S3 * Y * Z);
      SB[BBASE + 6*72 + lane] = tobf(nw * 0.5f * __fmaf_rn(3.f, Z * Z, -r2));
      SB[BBASE + 7*72 + lane] = tobf(nw * S3 * X * Z);
      SB[BBASE + 8*72 + lane] = tobf(nw * 0.5f * S3 * (X * X - Y * Y));
      // A rows: rbf[r] = sqrt2*e*[0.1, sin(k pi r), cos(k pi r)] (recurrence)
      float s1, c1;
      __sincosf(PIF * rn, &s1, &c1);
      SB[0 * 72 + lane]  = tobf(0.1f * f);
      float sk = s1, ck = c1;
      SB[1 * 72 + lane]  = tobf(f * sk);
      SB[17 * 72 + lane] = tobf(f * ck);
      #pragma unroll
      for (int k = 2; k <= 16; ++k) {
        float sn = __fmaf_rn(sk, c1, ck * s1);
        float cn = __fmaf_rn(ck, c1, -(sk * s1));
        sk = sn; ck = cn;
        SB[k * 72 + lane]        = tobf(f * sk);
        SB[(16 + k) * 72 + lane] = tobf(f * ck);
      }
    } else {
      // zero B column -> this point contributes nothing (A may be stale)
      #pragma unroll
      for (int h = 0; h < 9; ++h) SB[BBASE + h * 72 + lane] = 0;
    }
    // MFMA: A[m=r][k=p], B[k=p][n=h]; lane m=l&15, k=8*(l>>4)+j (+32 per k-group)
    #pragma unroll
    for (int g = 0; g < 2; ++g) {
      int cb = 8 * q + 32 * g;
      i32x4 bf = *(const i32x4*)&SB[BBASE + m * 72 + cb];
      i32x4 a0 = *(const i32x4*)&SB[(0  + m) * 72 + cb];
      mfma_acc(acc0, a0, bf);
      i32x4 a1 = *(const i32x4*)&SB[(16 + m) * 72 + cb];
      mfma_acc(acc1, a1, bf);
      i32x4 a2 = *(const i32x4*)&SB[(32 + m) * 72 + cb];
      mfma_acc(acc2, a2, bf);
    }
  }
  // MFMA -> VALU read hazard guard
  asm volatile("s_nop 7\n\ts_nop 7" : "+v"(acc0), "+v"(acc1), "+v"(acc2));

  // cross-wave reduction in LDS (wave-private regions)
  float* redw = (float*)&lds[w][0];
  if (m < 9) {
    #pragma unroll
    for (int t = 0; t < 4; ++t) {
      int row = 4 * q + t;                 // C/D: col=lane&15, row=(lane>>4)*4+t
      redw[(row +  0) * 9 + m] = acc0[t];
      redw[(row + 16) * 9 + m] = acc1[t];
      if (row + 32 < 33) redw[(row + 32) * 9 + m] = acc2[t];
    }
  }
  __syncthreads();
  float* pbb = pb + (size_t)blockIdx.x * PBSTR;
  for (int v = tid; v < 297; v += 256) {
    float s0 = ((const float*)&lds[0][0])[v] + ((const float*)&lds[1][0])[v];
    float s1 = ((const float*)&lds[2][0])[v] + ((const float*)&lds[3][0])[v];
    pbb[v] = s0 + s1;                      // plain store -- zero atomics
  }
}

// ---------------- K6: sum chunk partials -> out ----------------
__global__ __launch_bounds__(256) void enc_reduce(
    const float* __restrict__ pb, float* __restrict__ out, int nout) {
  int idx = blockIdx.x * 256 + threadIdx.x;
  if (idx >= nout) return;
  int a = idx / 297, v = idx - a * 297;
  const float* p = pb + (size_t)a * NCHUNK * PBSTR + v;
  float s = 0.f;
  #pragma unroll 8
  for (int k = 0; k < NCHUNK; ++k) s += p[(size_t)k * PBSTR];
  out[idx] = s;
}

extern "C" void kernel_launch(void* const* d_in, const int* in_sizes, int n_in,
                              void* d_out, int out_size, void* d_ws, size_t ws_size,
                              hipStream_t stream) {
  const float* nuc  = (const float*)d_in[0];
  // d_in[1] = atom_mask (unused by reference math)
  const float* grid = (const float*)d_in[2];
  const float* wts  = (const float*)d_in[3];
  const float* nn   = (const float*)d_in[4];
  int A = in_sizes[0] / 3;
  int N = in_sizes[2] / 3;
  long long t8 = (8LL * (long long)N) / (long long)A;
  unsigned T = (unsigned)(t8 < (long long)N ? t8 : (long long)N);

  // ws: [cnt A*S][b1 A][r2 A][thr A][hists A*S*NB1][ghist2 A*NB2]
  //     [pb A*NCHUNK*PBSTR floats][bits A*S*SCAP u32][pay A*S*SCAP uint2]
  unsigned* ws      = (unsigned*)d_ws;
  unsigned* cnt     = ws;
  unsigned* b1r     = cnt + A * SLICES;
  unsigned* r2r     = b1r + A;
  unsigned* thr     = r2r + A;
  unsigned* hists   = thr + A;
  unsigned* ghist2  = hists + (size_t)A * SLICES * NB1;
  float*    pb      = (float*)(ghist2 + (size_t)A * NB2);
  unsigned* bitsArr = (unsigned*)(pb + (size_t)A * NCHUNK * PBSTR);

  // per-slice quad range bounds the stored count -> overflow impossible
  int nq   = N >> 2;
  int qper = (nq + SLICES - 1) / SLICES;
  int SCAP = qper * 4 + 4;
  {
    long long head  = (long long)(bitsArr - ws);               // dwords
    long long avail = (long long)(ws_size / 4) - head;         // dwords
    long long need  = 3LL * SCAP * A * SLICES;                 // 1 + 2 dwords
    if (avail > 0 && need > avail) SCAP = (int)(avail / (3LL * A * SLICES));
    SCAP &= ~1;                                                // keep pay 8B-aligned
  }
  uint2* pay = (uint2*)(bitsArr + (size_t)A * SLICES * SCAP);
  float* out = (float*)d_out;
  int nout = A * 297;

  enc_hist_store<<<(A / AG) * SLICES,  256, 0, stream>>>(nuc, grid, wts, nn, N, hists,
                                                         cnt, bitsArr, pay, SCAP, ghist2);
  enc_scan1     <<<A,                  256, 0, stream>>>(hists, T, b1r, r2r);
  enc_fine      <<<A * SLICES,         256, 0, stream>>>(b1r, cnt, bitsArr, SCAP, ghist2);
  enc_scan2     <<<A,                  256, 0, stream>>>(ghist2, b1r, r2r, thr);
  enc_accum     <<<A * SLICES,         256, 0, stream>>>(thr, cnt, bitsArr, pay, SCAP, pb);
  enc_reduce    <<<(nout + 255) / 256, 256, 0, stream>>>(pb, out, nout);
}

// Round 19
// 57.453 us; speedup vs baseline: 1.1412x; 1.1412x over previous
//
#include <hip/hip_runtime.h>
#include <hip/hip_fp16.h>

// Encoder: per-atom top-T nearest grid points -> sum_t rbf[33] (x) (sh[9]*n*w)
// R17/R18 lessons: traffic cuts to hist_store don't help (not BW-bound);
// AG grouping kills TLP. The stall is the 4x serial ballot->LDS-atomic->shfl
// append chain per quad. R19 = R16 config + ONE change: single wave
// prefix-scan append (1 atomic/quad instead of 4 dependent rounds).
// 6 dispatches:
// K1 hist_store: full scan; 256-bin clamped coarse hist; prefix-scan append
//                of bits(4B) + payload(8B f16 dx,dy,dz,nw); zero ghist2 stripe
// K2 scan1     : per-atom: sum 32x256-bin hists -> b1, residual R2
// K3 fine      : fine hist bits[17:9] of crossing-bin points (bits-only)
// K4 scan2     : per-atom: scan 512-bin fine hist -> thr[a]
// K5 accum     : thr scalar; prefetch records; filter, features, bf16 MFMA,
//                LDS cross-wave reduce, one plain 297-float store per block
// K6 reduce    : sum 32 chunk-partials per atom -> out

typedef float f32x4 __attribute__((ext_vector_type(4)));
typedef int   i32x4 __attribute__((ext_vector_type(4)));

#define SLICES 32
#define NB1    256           // coarse bins (clamped)
#define NB2    512           // fine bins: bits[17:9] within crossing bin
#define CLAMP0 4000u         // bits>>18 below this (d2<~0.25) -> bin 0
#define NCHUNK SLICES        // accum chunks per atom (1 segment/block)
#define PBSTR  304           // partials row stride
#define CUT25  0x41C80000u   // __float_as_uint(25.0f) == CUTOFF^2 bits
#define WROWS  49            // accum: 33 A rows + 16 B rows per wave
#define BBASE  (33 * 72)     // B region offset (shorts)

__device__ __forceinline__ unsigned short tobf(float v) {
  return (unsigned short)((__float_as_uint(v) + 0x8000u) >> 16);
}

__device__ __forceinline__ unsigned pack2h(float a, float b) {
  __half2 h = __floats2half2_rn(a, b);
  return *reinterpret_cast<unsigned*>(&h);
}

__device__ __forceinline__ void mfma_acc(f32x4& d, i32x4 a, i32x4 b) {
  asm("v_mfma_f32_16x16x32_bf16 %0, %1, %2, %0" : "+v"(d) : "v"(a), "v"(b));
}

// ---------------- K1: full scan -> coarse hist + prefix-scan append ----------------
__global__ __launch_bounds__(256) void enc_hist_store(
    const float* __restrict__ nuc, const float* __restrict__ grid,
    const float* __restrict__ wv, const float* __restrict__ nv, int N,
    unsigned* __restrict__ hists, unsigned* __restrict__ cnt,
    unsigned* __restrict__ bitsArr, uint2* __restrict__ pay, int scap,
    unsigned* __restrict__ ghist2) {
  __shared__ unsigned lh[NB1];
  __shared__ unsigned s_cnt;
  int a = blockIdx.x / SLICES, s = blockIdx.x % SLICES;
  int tid = threadIdx.x, lane = tid & 63;
  if (tid < NB1) lh[tid] = 0;
  if (tid == 0) s_cnt = 0;
  { // zero this block's stripe of atom a's fine hist (written by K3 later)
    const int stripe = NB2 / SLICES;       // 16
    if (tid < stripe) ghist2[(size_t)a * NB2 + s * stripe + tid] = 0;
  }
  __syncthreads();

  float px = nuc[3*a+0], py = nuc[3*a+1], pz = nuc[3*a+2];
  unsigned* segb = bitsArr + (size_t)blockIdx.x * scap;
  uint2*    segp = pay     + (size_t)blockIdx.x * scap;
  const float4* G4 = (const float4*)grid;
  const float4* W4 = (const float4*)wv;
  const float4* V4 = (const float4*)nv;
  int nq = N >> 2;
  int qper = (nq + SLICES - 1) / SLICES;
  int qlo = s * qper, qhi = min(nq, qlo + qper);

  // uniform trip count: all 64 lanes stay active (prefix scan needs full wave)
  for (int qb = qlo; qb < qhi; qb += 256) {
    int qi = qb + tid;
    bool qv = qi < qhi;
    float dxs[4], dys[4], dzs[4], nws[4];
    unsigned bt[4];
    if (qv) {
      float4 A4 = G4[3*qi], B4 = G4[3*qi+1], C4 = G4[3*qi+2];
      float4 w4 = W4[qi], v4 = V4[qi];
      float xs[4] = {A4.x, A4.w, B4.z, C4.y};
      float ys[4] = {A4.y, B4.x, B4.w, C4.z};
      float zs[4] = {A4.z, B4.y, C4.x, C4.w};
      nws[0] = v4.x * w4.x; nws[1] = v4.y * w4.y;
      nws[2] = v4.z * w4.z; nws[3] = v4.w * w4.w;
      #pragma unroll
      for (int k = 0; k < 4; ++k) {
        float dx = px - xs[k], dy = py - ys[k], dz = pz - zs[k];
        dxs[k] = dx; dys[k] = dy; dzs[k] = dz;
        float d2 = __fmaf_rn(dx, dx, __fmaf_rn(dy, dy, __fmul_rn(dz, dz)));
        bt[k] = __float_as_uint(d2);
        if (bt[k] < CUT25) {
          int cb = (int)(bt[k] >> 18) - (int)CLAMP0;
          atomicAdd(&lh[cb > 0 ? cb : 0], 1u);
        }
      }
    } else {
      #pragma unroll
      for (int k = 0; k < 4; ++k) bt[k] = 0xFFFFFFFFu;
    }
    // single prefix-scan append (replaces 4 serial ballot+atomic rounds)
    unsigned csel = 0;
    #pragma unroll
    for (int k = 0; k < 4; ++k) csel += (bt[k] < CUT25) ? 1u : 0u;
    unsigned p = csel;
    #pragma unroll
    for (int d = 1; d < 64; d <<= 1) {
      unsigned t = __shfl_up(p, d);
      if (lane >= d) p += t;
    }
    unsigned wtot = __shfl(p, 63);         // wave total
    unsigned excl = p - csel;              // exclusive prefix
    unsigned base = 0;
    if (wtot) {
      if (lane == 0) base = atomicAdd(&s_cnt, wtot);
      base = __shfl(base, 0);
      unsigned pos = base + excl;
      #pragma unroll
      for (int k = 0; k < 4; ++k) {
        if (bt[k] < CUT25) {
          if (pos < (unsigned)scap) {
            segb[pos] = bt[k];
            segp[pos] = make_uint2(pack2h(dxs[k], dys[k]), pack2h(dzs[k], nws[k]));
          }
          ++pos;
        }
      }
    }
  }
  if (s == SLICES - 1) {                   // scalar tail (N % 4 points)
    for (int i = 4*nq + tid; i < N; i += 256) {
      float dx = px - grid[3*i+0], dy = py - grid[3*i+1], dz = pz - grid[3*i+2];
      float d2 = __fmaf_rn(dx, dx, __fmaf_rn(dy, dy, __fmul_rn(dz, dz)));
      unsigned bits = __float_as_uint(d2);
      bool sel = bits < CUT25;
      if (sel) {
        int cb = (int)(bits >> 18) - (int)CLAMP0;
        atomicAdd(&lh[cb > 0 ? cb : 0], 1u);
      }
      unsigned long long mm = __ballot(sel);
      if (mm) {
        int leader = __ffsll(mm) - 1;
        unsigned base = 0;
        if (lane == leader) base = atomicAdd(&s_cnt, (unsigned)__popcll(mm));
        base = __shfl(base, leader);
        if (sel) {
          unsigned pos = base + (unsigned)__popcll(mm & ((1ull << lane) - 1ull));
          if (pos < (unsigned)scap) {
            segb[pos] = bits;
            segp[pos] = make_uint2(pack2h(dx, dy), pack2h(dz, nv[i] * wv[i]));
          }
        }
      }
    }
  }
  __syncthreads();
  if (tid < NB1) hists[(size_t)blockIdx.x * NB1 + tid] = lh[tid];  // plain store
  if (tid == 0) cnt[blockIdx.x] = s_cnt;
}

// ---------------- K2: per-atom coarse scan -> b1, R2 ----------------
__global__ __launch_bounds__(256) void enc_scan1(
    const unsigned* __restrict__ hists, unsigned T,
    unsigned* __restrict__ b1r, unsigned* __restrict__ r2r) {
  __shared__ unsigned lh[NB1];
  __shared__ unsigned s_bin, s_pre;
  int a = blockIdx.x, tid = threadIdx.x;
  if (tid < NB1) {
    unsigned acc = 0;
    const unsigned* base = hists + (size_t)a * SLICES * NB1 + tid;
    #pragma unroll 8
    for (int t = 0; t < SLICES; ++t) acc += base[(size_t)t * NB1];
    lh[tid] = acc;
  }
  if (tid == 0) { s_bin = NB1 - 1; s_pre = 0; }
  __syncthreads();
  if (tid < 64) {
    int lane = tid, base = 4 * lane;
    unsigned h0 = lh[base], h1 = lh[base+1], h2 = lh[base+2], h3 = lh[base+3];
    unsigned ssum = h0 + h1 + h2 + h3;
    unsigned p = ssum;
    #pragma unroll
    for (int d = 1; d < 64; d <<= 1) {
      unsigned t = __shfl_up(p, d);
      if (lane >= d) p += t;
    }
    unsigned excl = p - ssum;
    if (excl < T && T <= p) {              // unique crossing lane
      unsigned cum = excl;
      unsigned hh[4] = {h0, h1, h2, h3};
      #pragma unroll
      for (int k = 0; k < 4; ++k) {
        if (cum + hh[k] >= T) { s_bin = (unsigned)(base + k); s_pre = cum; break; }
        cum += hh[k];
      }
    }
  }
  __syncthreads();
  if (tid == 0) { b1r[a] = s_bin; r2r[a] = T - s_pre; }
}

// ---------------- K3: fine hist of crossing-bin points (bits-only) ----------------
__global__ __launch_bounds__(256) void enc_fine(
    const unsigned* __restrict__ b1r, const unsigned* __restrict__ cnt,
    const unsigned* __restrict__ bitsArr, int scap,
    unsigned* __restrict__ ghist2) {
  int seg_id = blockIdx.x;
  int a = seg_id / SLICES;
  unsigned b1c = b1r[a];
  unsigned tb1 = b1c + CLAMP0;
  int total = min((int)cnt[seg_id], scap);
  const unsigned* segb = bitsArr + (size_t)seg_id * scap;
  unsigned* gh2 = ghist2 + (size_t)a * NB2;
  for (int i = threadIdx.x; i < total; i += 256) {
    unsigned bits = segb[i];
    unsigned cb = bits >> 18;
    bool match = b1c ? (cb == tb1) : (cb <= CLAMP0);  // bin0 = clamped region
    if (match) atomicAdd(&gh2[(bits >> 9) & (NB2 - 1)], 1u);
  }
}

// ---------------- K4: per-atom fine scan -> thr ----------------
__global__ __launch_bounds__(256) void enc_scan2(
    const unsigned* __restrict__ ghist2, const unsigned* __restrict__ b1r,
    const unsigned* __restrict__ r2r, unsigned* __restrict__ thr) {
  __shared__ unsigned lh2[NB2];
  __shared__ unsigned s_bin2;
  int a = blockIdx.x, tid = threadIdx.x;
  const unsigned* gh2 = ghist2 + (size_t)a * NB2;
  lh2[tid] = gh2[tid];
  lh2[tid + 256] = gh2[tid + 256];
  if (tid == 0) s_bin2 = NB2 - 1;
  __syncthreads();
  unsigned R = r2r[a];
  if (tid < 64) {                          // two-level scan over 512 bins
    int lane = tid, base = 8 * lane;
    unsigned hh[8], ssum = 0;
    #pragma unroll
    for (int k = 0; k < 8; ++k) { hh[k] = lh2[base + k]; ssum += hh[k]; }
    unsigned p = ssum;
    #pragma unroll
    for (int d = 1; d < 64; d <<= 1) {
      unsigned t = __shfl_up(p, d);
      if (lane >= d) p += t;
    }
    unsigned excl = p - ssum;
    if (excl < R && R <= p) {
      unsigned cum = excl;
      #pragma unroll
      for (int k = 0; k < 8; ++k) {
        if (cum + hh[k] >= R) { s_bin2 = (unsigned)(base + k); break; }
        cum += hh[k];
      }
    }
  }
  __syncthreads();
  if (tid == 0) thr[a] = ((b1r[a] + CLAMP0) << 9) | s_bin2;  // (bits>>9) <= thr
}

// ---------------- K5: MFMA accumulation -> per-block partials ----------------
__global__ __launch_bounds__(256, 5) void enc_accum(
    const unsigned* __restrict__ thrv, const unsigned* __restrict__ cnt,
    const unsigned* __restrict__ bitsArr, const uint2* __restrict__ pay,
    int scap, float* __restrict__ pb) {
  // per-wave 49-row x 72-short region: A rows 0..32, B rows 33..48.
  // MFMA a2 reads rows 32..47 -> feeds only discarded C rows. 28.2KB total.
  __shared__ __align__(16) unsigned short lds[4][WROWS * 72];
  int seg_id = blockIdx.x;
  int a = seg_id / SLICES;
  int tid = threadIdx.x, lane = tid & 63, w = tid >> 6;
  unsigned short* SB = &lds[w][0];

  { // zero this wave's region (A stale cols must not be NaN; 441 i32x4)
    i32x4 z = {0, 0, 0, 0};
    i32x4* zp = (i32x4*)SB;
    #pragma unroll
    for (int t = 0; t < 7; ++t) {
      int idx = lane + t * 64;
      if (idx < (WROWS * 72) / 8) zp[idx] = z;
    }
  }

  unsigned thr = thrv[a];                  // precomputed: no per-block scan
  int total = min((int)cnt[seg_id], scap);
  const unsigned* lstb = bitsArr + (size_t)seg_id * scap;
  const uint2*    lstp = pay     + (size_t)seg_id * scap;

  f32x4 acc0 = {0,0,0,0}, acc1 = {0,0,0,0}, acc2 = {0,0,0,0};
  int m = lane & 15, q = lane >> 4;
  const float SQRT2 = 1.41421356237309515f;
  const float PIF   = 3.14159265358979323846f;
  const float S3    = 1.73205080756887729f;

  // software prefetch: issue next record's loads before the ~600cy body
  int j0 = w * 64 + lane;
  unsigned bitsN = (j0 < total) ? lstb[j0] : 0xFFFFFFFFu;
  uint2 prN = make_uint2(0u, 0u);
  if (j0 < total) prN = lstp[j0];

  for (int jb = w * 64; jb < total; jb += 256) {
    unsigned bits = bitsN;
    uint2 pr = prN;
    int jn = jb + 256 + lane;
    if (jn < total) { bitsN = lstb[jn]; prN = lstp[jn]; }
    bool live = (jb + lane < total) && ((bits >> 9) <= thr);
    if (live) {
      float d2 = __uint_as_float(bits);
      __half2 hxy = *reinterpret_cast<const __half2*>(&pr.x);
      __half2 hzn = *reinterpret_cast<const __half2*>(&pr.y);
      float dx = __low2float(hxy), dy = __high2float(hxy);
      float dz = __low2float(hzn), nw = __high2float(hzn);
#if __has_builtin(__builtin_amdgcn_sqrtf)
      float rn = __builtin_amdgcn_sqrtf(d2) * 0.2f;
#else
      float rn = sqrtf(d2) * 0.2f;
#endif
      float x2 = rn * rn;
      float x6 = x2 * x2 * x2;
      float e  = __fmaf_rn(x6, __fmaf_rn(-21.f, x2, __fmaf_rn(48.f, rn, -28.f)), 1.f);
      float f  = SQRT2 * e;
#if __has_builtin(__builtin_amdgcn_rcpf)
      float inv = 0.2f * __builtin_amdgcn_rcpf(rn + 1e-15f);
#else
      float inv = 0.2f / (rn + 1e-15f);
#endif
      float X = dx * inv, Y = dy * inv, Z = dz * inv;
      float r2 = __fmaf_rn(X, X, __fmaf_rn(Y, Y, Z * Z));
      // B rows: v[h] = nw * sh[h]
      SB[BBASE + 0*72 + lane] = tobf(nw);
      SB[BBASE + 1*72 + lane] = tobf(nw * Y);
      SB[BBASE + 2*72 + lane] = tobf(nw * Z);
      SB[BBASE + 3*72 + lane] = tobf(nw * X);
      SB[BBASE + 4*72 + lane] = tobf(nw * S3 * X * Y);
      SB[BBASE + 5*72 + lane] = tobf(nw * S3 * Y * Z);
      SB[BBASE + 6*72 + lane] = tobf(nw * 0.5f * __fmaf_rn(3.f, Z * Z, -r2));
      SB[BBASE + 7*72 + lane] = tobf(nw * S3 * X * Z);
      SB[BBASE + 8*72 + lane] = tobf(nw * 0.5f * S3 * (X * X - Y * Y));
      // A rows: rbf[r] = sqrt2*e*[0.1, sin(k pi r), cos(k pi r)] (recurrence)
      float s1, c1;
      __sincosf(PIF * rn, &s1, &c1);
      SB[0 * 72 + lane]  = tobf(0.1f * f);
      float sk = s1, ck = c1;
      SB[1 * 72 + lane]  = tobf(f * sk);
      SB[17 * 72 + lane] = tobf(f * ck);
      #pragma unroll
      for (int k = 2; k <= 16; ++k) {
        float sn = __fmaf_rn(sk, c1, ck * s1);
        float cn = __fmaf_rn(ck, c1, -(sk * s1));
        sk = sn; ck = cn;
        SB[k * 72 + lane]        = tobf(f * sk);
        SB[(16 + k) * 72 + lane] = tobf(f * ck);
      }
    } else {
      // zero B column -> this point contributes nothing (A may be stale)
      #pragma unroll
      for (int h = 0; h < 9; ++h) SB[BBASE + h * 72 + lane] = 0;
    }
    // MFMA: A[m=r][k=p], B[k=p][n=h]; lane m=l&15, k=8*(l>>4)+j (+32 per k-group)
    #pragma unroll
    for (int g = 0; g < 2; ++g) {
      int cb = 8 * q + 32 * g;
      i32x4 bf = *(const i32x4*)&SB[BBASE + m * 72 + cb];
      i32x4 a0 = *(const i32x4*)&SB[(0  + m) * 72 + cb];
      mfma_acc(acc0, a0, bf);
      i32x4 a1 = *(const i32x4*)&SB[(16 + m) * 72 + cb];
      mfma_acc(acc1, a1, bf);
      i32x4 a2 = *(const i32x4*)&SB[(32 + m) * 72 + cb];
      mfma_acc(acc2, a2, bf);
    }
  }
  // MFMA -> VALU read hazard guard
  asm volatile("s_nop 7\n\ts_nop 7" : "+v"(acc0), "+v"(acc1), "+v"(acc2));

  // cross-wave reduction in LDS (wave-private regions)
  float* redw = (float*)&lds[w][0];
  if (m < 9) {
    #pragma unroll
    for (int t = 0; t < 4; ++t) {
      int row = 4 * q + t;                 // C/D: col=lane&15, row=(lane>>4)*4+t
      redw[(row +  0) * 9 + m] = acc0[t];
      redw[(row + 16) * 9 + m] = acc1[t];
      if (row + 32 < 33) redw[(row + 32) * 9 + m] = acc2[t];
    }
  }
  __syncthreads();
  float* pbb = pb + (size_t)blockIdx.x * PBSTR;
  for (int v = tid; v < 297; v += 256) {
    float s0 = ((const float*)&lds[0][0])[v] + ((const float*)&lds[1][0])[v];
    float s1 = ((const float*)&lds[2][0])[v] + ((const float*)&lds[3][0])[v];
    pbb[v] = s0 + s1;                      // plain store -- zero atomics
  }
}

// ---------------- K6: sum chunk partials -> out ----------------
__global__ __launch_bounds__(256) void enc_reduce(
    const float* __restrict__ pb, float* __restrict__ out, int nout) {
  int idx = blockIdx.x * 256 + threadIdx.x;
  if (idx >= nout) return;
  int a = idx / 297, v = idx - a * 297;
  const float* p = pb + (size_t)a * NCHUNK * PBSTR + v;
  float s = 0.f;
  #pragma unroll 8
  for (int k = 0; k < NCHUNK; ++k) s += p[(size_t)k * PBSTR];
  out[idx] = s;
}

extern "C" void kernel_launch(void* const* d_in, const int* in_sizes, int n_in,
                              void* d_out, int out_size, void* d_ws, size_t ws_size,
                              hipStream_t stream) {
  const float* nuc  = (const float*)d_in[0];
  // d_in[1] = atom_mask (unused by reference math)
  const float* grid = (const float*)d_in[2];
  const float* wts  = (const float*)d_in[3];
  const float* nn   = (const float*)d_in[4];
  int A = in_sizes[0] / 3;
  int N = in_sizes[2] / 3;
  long long t8 = (8LL * (long long)N) / (long long)A;
  unsigned T = (unsigned)(t8 < (long long)N ? t8 : (long long)N);

  // ws: [cnt A*S][b1 A][r2 A][thr A][hists A*S*NB1][ghist2 A*NB2]
  //     [pb A*NCHUNK*PBSTR floats][bits A*S*SCAP u32][pay A*S*SCAP uint2]
  unsigned* ws      = (unsigned*)d_ws;
  unsigned* cnt     = ws;
  unsigned* b1r     = cnt + A * SLICES;
  unsigned* r2r     = b1r + A;
  unsigned* thr     = r2r + A;
  unsigned* hists   = thr + A;
  unsigned* ghist2  = hists + (size_t)A * SLICES * NB1;
  float*    pb      = (float*)(ghist2 + (size_t)A * NB2);
  unsigned* bitsArr = (unsigned*)(pb + (size_t)A * NCHUNK * PBSTR);

  // per-slice quad range bounds the stored count -> overflow impossible
  int nq   = N >> 2;
  int qper = (nq + SLICES - 1) / SLICES;
  int SCAP = qper * 4 + 4;
  {
    long long head  = (long long)(bitsArr - ws);               // dwords
    long long avail = (long long)(ws_size / 4) - head;         // dwords
    long long need  = 3LL * SCAP * A * SLICES;                 // 1 + 2 dwords
    if (avail > 0 && need > avail) SCAP = (int)(avail / (3LL * A * SLICES));
    SCAP &= ~1;                                                // keep pay 8B-aligned
  }
  uint2* pay = (uint2*)(bitsArr + (size_t)A * SLICES * SCAP);
  float* out = (float*)d_out;
  int nout = A * 297;

  enc_hist_store<<<A * SLICES,         256, 0, stream>>>(nuc, grid, wts, nn, N, hists,
                                                         cnt, bitsArr, pay, SCAP, ghist2);
  enc_scan1     <<<A,                  256, 0, stream>>>(hists, T, b1r, r2r);
  enc_fine      <<<A * SLICES,         256, 0, stream>>>(b1r, cnt, bitsArr, SCAP, ghist2);
  enc_scan2     <<<A,                  256, 0, stream>>>(ghist2, b1r, r2r, thr);
  enc_accum     <<<A * SLICES,         256, 0, stream>>>(thr, cnt, bitsArr, pay, SCAP, pb);
  enc_reduce    <<<(nout + 255) / 256, 256, 0, stream>>>(pb, out, nout);
}

// Round 20
// 54.905 us; speedup vs baseline: 1.1942x; 1.0464x over previous
//
#include <hip/hip_runtime.h>
#include <hip/hip_fp16.h>

// Encoder: per-atom top-T nearest grid points -> sum_t rbf[33] (x) (sh[9]*n*w)
// R19: hist_store insensitive to traffic/occupancy/append levers (latency-
// structure floor). R20 attacks accum's quantified LDS-pipe floor (42
// ds_write_b16 per 64-pt iter ~= 13.5us): 2 points/lane column packing ->
// 21 ds_write_b32 + 21 cvt_pk per point-pair row set, paired uint2/uint4
// record loads. 12 MFMAs per 128-col iteration (per-point count unchanged).
// 6 dispatches:
// K1 hist_store: full scan; 256-bin clamped coarse hist; prefix-scan append
// K2 scan1     : per-atom: sum 32x256-bin hists -> b1, residual R2
// K3 fine      : fine hist bits[17:9] of crossing-bin points (bits-only)
// K4 scan2     : per-atom: scan 512-bin fine hist -> thr[a]
// K5 accum     : 2-pt/lane packed transpose, bf16 MFMA, LDS reduce, 1 store
// K6 reduce    : sum 32 chunk-partials per atom -> out

typedef float f32x4 __attribute__((ext_vector_type(4)));
typedef int   i32x4 __attribute__((ext_vector_type(4)));

#define SLICES 32
#define NB1    256           // coarse bins (clamped)
#define NB2    512           // fine bins: bits[17:9] within crossing bin
#define CLAMP0 4000u         // bits>>18 below this (d2<~0.25) -> bin 0
#define NCHUNK SLICES        // accum chunks per atom (1 segment/block)
#define PBSTR  304           // partials row stride
#define CUT25  0x41C80000u   // __float_as_uint(25.0f) == CUTOFF^2 bits
#define WROWS  49            // accum: 33 A rows + 16 B rows per wave
#define CSTR   136           // accum LDS row stride (128 cols + pad), 272B (16B mult)
#define CSTRD  (CSTR / 2)    // row stride in dwords (68)

__device__ __forceinline__ unsigned short tobf(float v) {
  return (unsigned short)((__float_as_uint(v) + 0x8000u) >> 16);
}

__device__ __forceinline__ unsigned pack2h(float a, float b) {
  __half2 h = __floats2half2_rn(a, b);
  return *reinterpret_cast<unsigned*>(&h);
}

// packed bf16 pair: {lo16: bf16(a), hi16: bf16(b)} (order-consistent A/B use)
__device__ __forceinline__ unsigned pkbf(float a, float b) {
  unsigned r;
  asm("v_cvt_pk_bf16_f32 %0, %1, %2" : "=v"(r) : "v"(a), "v"(b));
  return r;
}

__device__ __forceinline__ void mfma_acc(f32x4& d, i32x4 a, i32x4 b) {
  asm("v_mfma_f32_16x16x32_bf16 %0, %1, %2, %0" : "+v"(d) : "v"(a), "v"(b));
}

// ---------------- K1: full scan -> coarse hist + prefix-scan append ----------------
__global__ __launch_bounds__(256) void enc_hist_store(
    const float* __restrict__ nuc, const float* __restrict__ grid,
    const float* __restrict__ wv, const float* __restrict__ nv, int N,
    unsigned* __restrict__ hists, unsigned* __restrict__ cnt,
    unsigned* __restrict__ bitsArr, uint2* __restrict__ pay, int scap,
    unsigned* __restrict__ ghist2) {
  __shared__ unsigned lh[NB1];
  __shared__ unsigned s_cnt;
  int a = blockIdx.x / SLICES, s = blockIdx.x % SLICES;
  int tid = threadIdx.x, lane = tid & 63;
  if (tid < NB1) lh[tid] = 0;
  if (tid == 0) s_cnt = 0;
  { // zero this block's stripe of atom a's fine hist (written by K3 later)
    const int stripe = NB2 / SLICES;       // 16
    if (tid < stripe) ghist2[(size_t)a * NB2 + s * stripe + tid] = 0;
  }
  __syncthreads();

  float px = nuc[3*a+0], py = nuc[3*a+1], pz = nuc[3*a+2];
  unsigned* segb = bitsArr + (size_t)blockIdx.x * scap;
  uint2*    segp = pay     + (size_t)blockIdx.x * scap;
  const float4* G4 = (const float4*)grid;
  const float4* W4 = (const float4*)wv;
  const float4* V4 = (const float4*)nv;
  int nq = N >> 2;
  int qper = (nq + SLICES - 1) / SLICES;
  int qlo = s * qper, qhi = min(nq, qlo + qper);

  // uniform trip count: all 64 lanes stay active (prefix scan needs full wave)
  for (int qb = qlo; qb < qhi; qb += 256) {
    int qi = qb + tid;
    bool qv = qi < qhi;
    float dxs[4], dys[4], dzs[4], nws[4];
    unsigned bt[4];
    if (qv) {
      float4 A4 = G4[3*qi], B4 = G4[3*qi+1], C4 = G4[3*qi+2];
      float4 w4 = W4[qi], v4 = V4[qi];
      float xs[4] = {A4.x, A4.w, B4.z, C4.y};
      float ys[4] = {A4.y, B4.x, B4.w, C4.z};
      float zs[4] = {A4.z, B4.y, C4.x, C4.w};
      nws[0] = v4.x * w4.x; nws[1] = v4.y * w4.y;
      nws[2] = v4.z * w4.z; nws[3] = v4.w * w4.w;
      #pragma unroll
      for (int k = 0; k < 4; ++k) {
        float dx = px - xs[k], dy = py - ys[k], dz = pz - zs[k];
        dxs[k] = dx; dys[k] = dy; dzs[k] = dz;
        float d2 = __fmaf_rn(dx, dx, __fmaf_rn(dy, dy, __fmul_rn(dz, dz)));
        bt[k] = __float_as_uint(d2);
        if (bt[k] < CUT25) {
          int cb = (int)(bt[k] >> 18) - (int)CLAMP0;
          atomicAdd(&lh[cb > 0 ? cb : 0], 1u);
        }
      }
    } else {
      #pragma unroll
      for (int k = 0; k < 4; ++k) bt[k] = 0xFFFFFFFFu;
    }
    // single prefix-scan append (one LDS atomic per wave per quad-round)
    unsigned csel = 0;
    #pragma unroll
    for (int k = 0; k < 4; ++k) csel += (bt[k] < CUT25) ? 1u : 0u;
    unsigned p = csel;
    #pragma unroll
    for (int d = 1; d < 64; d <<= 1) {
      unsigned t = __shfl_up(p, d);
      if (lane >= d) p += t;
    }
    unsigned wtot = __shfl(p, 63);         // wave total
    unsigned excl = p - csel;              // exclusive prefix
    unsigned base = 0;
    if (wtot) {
      if (lane == 0) base = atomicAdd(&s_cnt, wtot);
      base = __shfl(base, 0);
      unsigned pos = base + excl;
      #pragma unroll
      for (int k = 0; k < 4; ++k) {
        if (bt[k] < CUT25) {
          if (pos < (unsigned)scap) {
            segb[pos] = bt[k];
            segp[pos] = make_uint2(pack2h(dxs[k], dys[k]), pack2h(dzs[k], nws[k]));
          }
          ++pos;
        }
      }
    }
  }
  if (s == SLICES - 1) {                   // scalar tail (N % 4 points)
    for (int i = 4*nq + tid; i < N; i += 256) {
      float dx = px - grid[3*i+0], dy = py - grid[3*i+1], dz = pz - grid[3*i+2];
      float d2 = __fmaf_rn(dx, dx, __fmaf_rn(dy, dy, __fmul_rn(dz, dz)));
      unsigned bits = __float_as_uint(d2);
      bool sel = bits < CUT25;
      if (sel) {
        int cb = (int)(bits >> 18) - (int)CLAMP0;
        atomicAdd(&lh[cb > 0 ? cb : 0], 1u);
      }
      unsigned long long mm = __ballot(sel);
      if (mm) {
        int leader = __ffsll(mm) - 1;
        unsigned base = 0;
        if (lane == leader) base = atomicAdd(&s_cnt, (unsigned)__popcll(mm));
        base = __shfl(base, leader);
        if (sel) {
          unsigned pos = base + (unsigned)__popcll(mm & ((1ull << lane) - 1ull));
          if (pos < (unsigned)scap) {
            segb[pos] = bits;
            segp[pos] = make_uint2(pack2h(dx, dy), pack2h(dz, nv[i] * wv[i]));
          }
        }
      }
    }
  }
  __syncthreads();
  if (tid < NB1) hists[(size_t)blockIdx.x * NB1 + tid] = lh[tid];  // plain store
  if (tid == 0) cnt[blockIdx.x] = s_cnt;
}

// ---------------- K2: per-atom coarse scan -> b1, R2 ----------------
__global__ __launch_bounds__(256) void enc_scan1(
    const unsigned* __restrict__ hists, unsigned T,
    unsigned* __restrict__ b1r, unsigned* __restrict__ r2r) {
  __shared__ unsigned lh[NB1];
  __shared__ unsigned s_bin, s_pre;
  int a = blockIdx.x, tid = threadIdx.x;
  if (tid < NB1) {
    unsigned acc = 0;
    const unsigned* base = hists + (size_t)a * SLICES * NB1 + tid;
    #pragma unroll 8
    for (int t = 0; t < SLICES; ++t) acc += base[(size_t)t * NB1];
    lh[tid] = acc;
  }
  if (tid == 0) { s_bin = NB1 - 1; s_pre = 0; }
  __syncthreads();
  if (tid < 64) {
    int lane = tid, base = 4 * lane;
    unsigned h0 = lh[base], h1 = lh[base+1], h2 = lh[base+2], h3 = lh[base+3];
    unsigned ssum = h0 + h1 + h2 + h3;
    unsigned p = ssum;
    #pragma unroll
    for (int d = 1; d < 64; d <<= 1) {
      unsigned t = __shfl_up(p, d);
      if (lane >= d) p += t;
    }
    unsigned excl = p - ssum;
    if (excl < T && T <= p) {              // unique crossing lane
      unsigned cum = excl;
      unsigned hh[4] = {h0, h1, h2, h3};
      #pragma unroll
      for (int k = 0; k < 4; ++k) {
        if (cum + hh[k] >= T) { s_bin = (unsigned)(base + k); s_pre = cum; break; }
        cum += hh[k];
      }
    }
  }
  __syncthreads();
  if (tid == 0) { b1r[a] = s_bin; r2r[a] = T - s_pre; }
}

// ---------------- K3: fine hist of crossing-bin points (bits-only) ----------------
__global__ __launch_bounds__(256) void enc_fine(
    const unsigned* __restrict__ b1r, const unsigned* __restrict__ cnt,
    const unsigned* __restrict__ bitsArr, int scap,
    unsigned* __restrict__ ghist2) {
  int seg_id = blockIdx.x;
  int a = seg_id / SLICES;
  unsigned b1c = b1r[a];
  unsigned tb1 = b1c + CLAMP0;
  int total = min((int)cnt[seg_id], scap);
  const unsigned* segb = bitsArr + (size_t)seg_id * scap;
  unsigned* gh2 = ghist2 + (size_t)a * NB2;
  for (int i = threadIdx.x; i < total; i += 256) {
    unsigned bits = segb[i];
    unsigned cb = bits >> 18;
    bool match = b1c ? (cb == tb1) : (cb <= CLAMP0);  // bin0 = clamped region
    if (match) atomicAdd(&gh2[(bits >> 9) & (NB2 - 1)], 1u);
  }
}

// ---------------- K4: per-atom fine scan -> thr ----------------
__global__ __launch_bounds__(256) void enc_scan2(
    const unsigned* __restrict__ ghist2, const unsigned* __restrict__ b1r,
    const unsigned* __restrict__ r2r, unsigned* __restrict__ thr) {
  __shared__ unsigned lh2[NB2];
  __shared__ unsigned s_bin2;
  int a = blockIdx.x, tid = threadIdx.x;
  const unsigned* gh2 = ghist2 + (size_t)a * NB2;
  lh2[tid] = gh2[tid];
  lh2[tid + 256] = gh2[tid + 256];
  if (tid == 0) s_bin2 = NB2 - 1;
  __syncthreads();
  unsigned R = r2r[a];
  if (tid < 64) {                          // two-level scan over 512 bins
    int lane = tid, base = 8 * lane;
    unsigned hh[8], ssum = 0;
    #pragma unroll
    for (int k = 0; k < 8; ++k) { hh[k] = lh2[base + k]; ssum += hh[k]; }
    unsigned p = ssum;
    #pragma unroll
    for (int d = 1; d < 64; d <<= 1) {
      unsigned t = __shfl_up(p, d);
      if (lane >= d) p += t;
    }
    unsigned excl = p - ssum;
    if (excl < R && R <= p) {
      unsigned cum = excl;
      #pragma unroll
      for (int k = 0; k < 8; ++k) {
        if (cum + hh[k] >= R) { s_bin2 = (unsigned)(base + k); break; }
        cum += hh[k];
      }
    }
  }
  __syncthreads();
  if (tid == 0) thr[a] = ((b1r[a] + CLAMP0) << 9) | s_bin2;  // (bits>>9) <= thr
}

// ---------------- K5: MFMA accumulation, 2 points/lane packed ----------------
__global__ __launch_bounds__(256, 3) void enc_accum(
    const unsigned* __restrict__ thrv, const unsigned* __restrict__ cnt,
    const unsigned* __restrict__ bitsArr, const uint2* __restrict__ pay,
    int scap, float* __restrict__ pb) {
  // per-wave 49-row x 136-short region (128 point-cols + pad; 272B rows).
  // A rows 0..32, B rows 33..48 (MFMA a2 reads rows 32..47 -> discarded C).
  __shared__ __align__(16) unsigned short lds[4][WROWS * CSTR];  // 53.3 KB
  int seg_id = blockIdx.x;
  int a = seg_id / SLICES;
  int tid = threadIdx.x, lane = tid & 63, w = tid >> 6;
  unsigned short* SB = &lds[w][0];
  unsigned* SBd = (unsigned*)SB;

  { // zero this wave's region (stale A cols must stay finite)
    i32x4 z = {0, 0, 0, 0};
    i32x4* zp = (i32x4*)SB;
    #pragma unroll
    for (int t = 0; t < 14; ++t) {
      int idx = lane + t * 64;
      if (idx < (WROWS * CSTR) / 8) zp[idx] = z;
    }
  }

  unsigned thr = thrv[a];
  int total = min((int)cnt[seg_id], scap);
  const unsigned* lstb = bitsArr + (size_t)seg_id * scap;
  const uint2*    lstp = pay     + (size_t)seg_id * scap;

  f32x4 acc0 = {0,0,0,0}, acc1 = {0,0,0,0}, acc2 = {0,0,0,0};
  int m = lane & 15, q = lane >> 4;
  const float SQRT2 = 1.41421356237309515f;
  const float PIF   = 3.14159265358979323846f;
  const float S3    = 1.73205080756887729f;

  // prefetch next pair of records (uint2 bits + uint4 payload per lane)
  int jp = w * 128 + 2 * lane;
  uint2 b2N = make_uint2(0xFFFFFFFFu, 0xFFFFFFFFu);
  uint4 p4N = make_uint4(0u, 0u, 0u, 0u);
  if (jp < total) {
    b2N = *reinterpret_cast<const uint2*>(&lstb[jp]);
    p4N = *reinterpret_cast<const uint4*>(&lstp[jp]);
  }

  for (int jb = w * 128; jb < total; jb += 512) {
    uint2 b2 = b2N; uint4 p4 = p4N;
    int jn = jb + 512 + 2 * lane;
    if (jn < total) {
      b2N = *reinterpret_cast<const uint2*>(&lstb[jn]);
      p4N = *reinterpret_cast<const uint4*>(&lstp[jn]);
    }
    int jj = jb + 2 * lane;
    bool live0 = (jj     < total) && ((b2.x >> 9) <= thr);
    bool live1 = (jj + 1 < total) && ((b2.y >> 9) <= thr);

    // sanitize dead halves: finite math, exact-zero outputs (f=0, nw=0)
    float d20 = live0 ? __uint_as_float(b2.x) : 1.0f;
    float d21 = live1 ? __uint_as_float(b2.y) : 1.0f;
    __half2 hxy0 = *reinterpret_cast<const __half2*>(&p4.x);
    __half2 hzn0 = *reinterpret_cast<const __half2*>(&p4.y);
    __half2 hxy1 = *reinterpret_cast<const __half2*>(&p4.z);
    __half2 hzn1 = *reinterpret_cast<const __half2*>(&p4.w);
    float dx0 = live0 ? __low2float(hxy0) : 0.f;
    float dy0 = live0 ? __high2float(hxy0) : 0.f;
    float dz0 = live0 ? __low2float(hzn0) : 0.f;
    float nw0 = live0 ? __high2float(hzn0) : 0.f;
    float dx1 = live1 ? __low2float(hxy1) : 0.f;
    float dy1 = live1 ? __high2float(hxy1) : 0.f;
    float dz1 = live1 ? __low2float(hzn1) : 0.f;
    float nw1 = live1 ? __high2float(hzn1) : 0.f;

#if __has_builtin(__builtin_amdgcn_sqrtf)
    float rn0 = __builtin_amdgcn_sqrtf(d20) * 0.2f;
    float rn1 = __builtin_amdgcn_sqrtf(d21) * 0.2f;
#else
    float rn0 = sqrtf(d20) * 0.2f;
    float rn1 = sqrtf(d21) * 0.2f;
#endif
    float x20 = rn0 * rn0, x21 = rn1 * rn1;
    float x60 = x20 * x20 * x20, x61 = x21 * x21 * x21;
    float e0 = __fmaf_rn(x60, __fmaf_rn(-21.f, x20, __fmaf_rn(48.f, rn0, -28.f)), 1.f);
    float e1 = __fmaf_rn(x61, __fmaf_rn(-21.f, x21, __fmaf_rn(48.f, rn1, -28.f)), 1.f);
    float f0 = live0 ? SQRT2 * e0 : 0.f;
    float f1 = live1 ? SQRT2 * e1 : 0.f;
#if __has_builtin(__builtin_amdgcn_rcpf)
    float inv0 = 0.2f * __builtin_amdgcn_rcpf(rn0 + 1e-15f);
    float inv1 = 0.2f * __builtin_amdgcn_rcpf(rn1 + 1e-15f);
#else
    float inv0 = 0.2f / (rn0 + 1e-15f);
    float inv1 = 0.2f / (rn1 + 1e-15f);
#endif
    float X0 = dx0 * inv0, Y0 = dy0 * inv0, Z0 = dz0 * inv0;
    float X1 = dx1 * inv1, Y1 = dy1 * inv1, Z1 = dz1 * inv1;
    float r20 = __fmaf_rn(X0, X0, __fmaf_rn(Y0, Y0, Z0 * Z0));
    float r21 = __fmaf_rn(X1, X1, __fmaf_rn(Y1, Y1, Z1 * Z1));

    // B rows (33..41): packed dword covers both columns (zero when dead)
    SBd[(33+0)*CSTRD + lane] = pkbf(nw0,            nw1);
    SBd[(33+1)*CSTRD + lane] = pkbf(nw0 * Y0,       nw1 * Y1);
    SBd[(33+2)*CSTRD + lane] = pkbf(nw0 * Z0,       nw1 * Z1);
    SBd[(33+3)*CSTRD + lane] = pkbf(nw0 * X0,       nw1 * X1);
    SBd[(33+4)*CSTRD + lane] = pkbf(nw0 * S3*X0*Y0, nw1 * S3*X1*Y1);
    SBd[(33+5)*CSTRD + lane] = pkbf(nw0 * S3*Y0*Z0, nw1 * S3*Y1*Z1);
    SBd[(33+6)*CSTRD + lane] = pkbf(nw0 * 0.5f*__fmaf_rn(3.f, Z0*Z0, -r20),
                                    nw1 * 0.5f*__fmaf_rn(3.f, Z1*Z1, -r21));
    SBd[(33+7)*CSTRD + lane] = pkbf(nw0 * S3*X0*Z0, nw1 * S3*X1*Z1);
    SBd[(33+8)*CSTRD + lane] = pkbf(nw0 * 0.5f*S3*(X0*X0 - Y0*Y0),
                                    nw1 * 0.5f*S3*(X1*X1 - Y1*Y1));
    // A rows: rbf (both columns packed); recurrence per point
    float s10, c10, s11, c11;
    __sincosf(PIF * rn0, &s10, &c10);
    __sincosf(PIF * rn1, &s11, &c11);
    SBd[0*CSTRD + lane]  = pkbf(0.1f * f0, 0.1f * f1);
    float sk0 = s10, ck0 = c10, sk1 = s11, ck1 = c11;
    SBd[1*CSTRD + lane]  = pkbf(f0 * sk0, f1 * sk1);
    SBd[17*CSTRD + lane] = pkbf(f0 * ck0, f1 * ck1);
    #pragma unroll
    for (int k = 2; k <= 16; ++k) {
      float sn0 = __fmaf_rn(sk0, c10, ck0 * s10);
      float cn0 = __fmaf_rn(ck0, c10, -(sk0 * s10));
      float sn1 = __fmaf_rn(sk1, c11, ck1 * s11);
      float cn1 = __fmaf_rn(ck1, c11, -(sk1 * s11));
      sk0 = sn0; ck0 = cn0; sk1 = sn1; ck1 = cn1;
      SBd[k*CSTRD + lane]      = pkbf(f0 * sk0, f1 * sk1);
      SBd[(16+k)*CSTRD + lane] = pkbf(f0 * ck0, f1 * ck1);
    }
    // MFMA over 4 k-groups (128 cols): A[m=r][k], B row 33+m; cb in shorts
    #pragma unroll
    for (int g = 0; g < 4; ++g) {
      int cb = 8 * q + 32 * g;
      i32x4 bf = *(const i32x4*)&SB[(33 + m) * CSTR + cb];
      i32x4 a0 = *(const i32x4*)&SB[(0  + m) * CSTR + cb];
      mfma_acc(acc0, a0, bf);
      i32x4 a1 = *(const i32x4*)&SB[(16 + m) * CSTR + cb];
      mfma_acc(acc1, a1, bf);
      i32x4 a2 = *(const i32x4*)&SB[(32 + m) * CSTR + cb];
      mfma_acc(acc2, a2, bf);
    }
  }
  // MFMA -> VALU read hazard guard
  asm volatile("s_nop 7\n\ts_nop 7" : "+v"(acc0), "+v"(acc1), "+v"(acc2));

  // cross-wave reduction in LDS (wave-private regions)
  float* redw = (float*)&lds[w][0];
  if (m < 9) {
    #pragma unroll
    for (int t = 0; t < 4; ++t) {
      int row = 4 * q + t;                 // C/D: col=lane&15, row=(lane>>4)*4+t
      redw[(row +  0) * 9 + m] = acc0[t];
      redw[(row + 16) * 9 + m] = acc1[t];
      if (row + 32 < 33) redw[(row + 32) * 9 + m] = acc2[t];
    }
  }
  __syncthreads();
  float* pbb = pb + (size_t)blockIdx.x * PBSTR;
  for (int v = tid; v < 297; v += 256) {
    float s0 = ((const float*)&lds[0][0])[v] + ((const float*)&lds[1][0])[v];
    float s1 = ((const float*)&lds[2][0])[v] + ((const float*)&lds[3][0])[v];
    pbb[v] = s0 + s1;                      // plain store -- zero atomics
  }
}

// ---------------- K6: sum chunk partials -> out ----------------
__global__ __launch_bounds__(256) void enc_reduce(
    const float* __restrict__ pb, float* __restrict__ out, int nout) {
  int idx = blockIdx.x * 256 + threadIdx.x;
  if (idx >= nout) return;
  int a = idx / 297, v = idx - a * 297;
  const float* p = pb + (size_t)a * NCHUNK * PBSTR + v;
  float s = 0.f;
  #pragma unroll 8
  for (int k = 0; k < NCHUNK; ++k) s += p[(size_t)k * PBSTR];
  out[idx] = s;
}

extern "C" void kernel_launch(void* const* d_in, const int* in_sizes, int n_in,
                              void* d_out, int out_size, void* d_ws, size_t ws_size,
                              hipStream_t stream) {
  const float* nuc  = (const float*)d_in[0];
  // d_in[1] = atom_mask (unused by reference math)
  const float* grid = (const float*)d_in[2];
  const float* wts  = (const float*)d_in[3];
  const float* nn   = (const float*)d_in[4];
  int A = in_sizes[0] / 3;
  int N = in_sizes[2] / 3;
  long long t8 = (8LL * (long long)N) / (long long)A;
  unsigned T = (unsigned)(t8 < (long long)N ? t8 : (long long)N);

  // ws: [cnt A*S][b1 A][r2 A][thr A][hists A*S*NB1][ghist2 A*NB2]
  //     [pb A*NCHUNK*PBSTR floats][bits A*S*SCAP u32][pay A*S*SCAP uint2]
  unsigned* ws      = (unsigned*)d_ws;
  unsigned* cnt     = ws;
  unsigned* b1r     = cnt + A * SLICES;
  unsigned* r2r     = b1r + A;
  unsigned* thr     = r2r + A;
  unsigned* hists   = thr + A;
  unsigned* ghist2  = hists + (size_t)A * SLICES * NB1;
  float*    pb      = (float*)(ghist2 + (size_t)A * NB2);
  unsigned* bitsArr = (unsigned*)(pb + (size_t)A * NCHUNK * PBSTR);

  // per-slice quad range bounds the stored count -> overflow impossible
  int nq   = N >> 2;
  int qper = (nq + SLICES - 1) / SLICES;
  int SCAP = qper * 4 + 4;
  {
    long long head  = (long long)(bitsArr - ws);               // dwords
    long long avail = (long long)(ws_size / 4) - head;         // dwords
    long long need  = 3LL * SCAP * A * SLICES;                 // 1 + 2 dwords
    if (avail > 0 && need > avail) SCAP = (int)(avail / (3LL * A * SLICES));
    SCAP &= ~1;                                                // keep pay 16B-aligned
  }
  uint2* pay = (uint2*)(bitsArr + (size_t)A * SLICES * SCAP);
  float* out = (float*)d_out;
  int nout = A * 297;

  enc_hist_store<<<A * SLICES,         256, 0, stream>>>(nuc, grid, wts, nn, N, hists,
                                                         cnt, bitsArr, pay, SCAP, ghist2);
  enc_scan1     <<<A,                  256, 0, stream>>>(hists, T, b1r, r2r);
  enc_fine      <<<A * SLICES,         256, 0, stream>>>(b1r, cnt, bitsArr, SCAP, ghist2);
  enc_scan2     <<<A,                  256, 0, stream>>>(ghist2, b1r, r2r, thr);
  enc_accum     <<<A * SLICES,         256, 0, stream>>>(thr, cnt, bitsArr, pay, SCAP, pb);
  enc_reduce    <<<(nout + 255) / 256, 256, 0, stream>>>(pb, out, nout);
}